// Round 4
// baseline (183.497 us; speedup 1.0000x reference)
//
#include <hip/hip_runtime.h>
#include <math.h>

typedef unsigned short u16;
typedef unsigned int u32;
typedef __attribute__((ext_vector_type(4))) float f32x4;
typedef __attribute__((ext_vector_type(16))) float f32x16;
typedef __attribute__((ext_vector_type(8))) short s16x8;
typedef __attribute__((ext_vector_type(4))) unsigned short u16x4;

#define T_ 2048
#define C_ 1024

// fp32 -> bf16, round-half-up (max err 0.5 ulp, values always finite here)
__device__ __forceinline__ u16 f2b(float f) {
  u32 u = __builtin_bit_cast(u32, f);
  return (u16)((u + 0x8000u) >> 16);
}

__device__ __forceinline__ s16x8 pack8(float4 a, float4 b) {
  s16x8 r;
  r[0] = (short)f2b(a.x); r[1] = (short)f2b(a.y);
  r[2] = (short)f2b(a.z); r[3] = (short)f2b(a.w);
  r[4] = (short)f2b(b.x); r[5] = (short)f2b(b.y);
  r[6] = (short)f2b(b.z); r[7] = (short)f2b(b.w);
  return r;
}

// ---------------- kernel 0: weights fp32 [1024][64] x3 -> Wt bf16 [192][1024]
// transposed (k-contiguous), via LDS tile transpose (coalesced both sides).
// Softmax scale 1/8 AND log2(e) folded into W_q (softmax done in exp2 domain).
__global__ __launch_bounds__(256) void wconv(const float* __restrict__ Wq,
                                             const float* __restrict__ Wk,
                                             const float* __restrict__ Wv,
                                             u16* __restrict__ Wt) {
  __shared__ u16 t[64][68];
  const int bm = blockIdx.x >> 4;   // matrix 0..2
  const int kt = blockIdx.x & 15;   // k-tile of 64
  const float* src = (bm == 0) ? Wq : ((bm == 1) ? Wk : Wv);
  const float scale = (bm == 0) ? 0.18033688f : 1.0f;  // 0.125 * log2(e)
  const int krow = threadIdx.x >> 2;        // 0..63
  const int c0 = (threadIdx.x & 3) * 16;    // 0,16,32,48
  const float* sp = src + (size_t)(kt * 64 + krow) * 64 + c0;
#pragma unroll
  for (int i = 0; i < 4; ++i) {
    float4 v = *(const float4*)(sp + i * 4);
    t[c0 + i * 4 + 0][krow] = f2b(v.x * scale);
    t[c0 + i * 4 + 1][krow] = f2b(v.y * scale);
    t[c0 + i * 4 + 2][krow] = f2b(v.z * scale);
    t[c0 + i * 4 + 3][krow] = f2b(v.w * scale);
  }
  __syncthreads();
  const int n = threadIdx.x >> 2;
  const int koff = (threadIdx.x & 3) * 16;
  u16* dst = Wt + (size_t)(bm * 64 + n) * C_ + kt * 64 + koff;
#pragma unroll
  for (int i = 0; i < 4; ++i)
    *(u16x4*)(dst + i * 4) = *(const u16x4*)(&t[n][koff + i * 4]);
}

// ---------------- kernel 1: qkv projection, W-STATIONARY.
// out^T = Wt (A, held in 128 VGPRs per wave for one K-half) x x^T (B, from a
// 64 KB LDS x-tile). Block = 768 threads = 12 waves = 6 n-groups x 2 K-halves.
// Grid 256 (1 block/CU, 3 waves/SIMD). K-halves merged via LDS (aliased into
// the x-tile, barrier-separated). No global load feeds an MFMA in the K-loop.
__global__ __launch_bounds__(768, 3) void proj(const float* __restrict__ x,
                                               const u16* __restrict__ Wt,
                                               u16* __restrict__ qo,
                                               u16* __restrict__ ko,
                                               u16* __restrict__ vt) {
  __shared__ __align__(16) char lds[65536];
  u16* tile = (u16*)lds;    // [32 rows][1024 k] bf16, 16B-chunk XOR swizzle
  float* mb = (float*)lds;  // merge buf [6][32][33] fp32, aliased (barriers)
  const int tid = threadIdx.x;
  const int wave = tid >> 6, lane = tid & 63;
  const int ng = wave % 6;   // n-group: W rows 32*ng .. 32*ng+31
  const int kh = wave / 6;   // K-half: k in [512*kh, 512*kh+512)
  const int l31 = lane & 31, half = lane >> 5;
  const int m0 = blockIdx.x * 64;

  // A frags (loaded ONCE): A[m=l31][k=8*half+i] per ks, 16B contiguous
  const u16* wp = Wt + (size_t)(32 * ng + l31) * C_ + 512 * kh + 8 * half;
  s16x8 wA[32];
#pragma unroll
  for (int ks = 0; ks < 32; ++ks)
    wA[ks] = *(const s16x8*)(wp + 16 * ks);

  for (int mt = 0; mt < 2; ++mt) {
    const int row0 = m0 + 32 * mt;
    // ---- stage x tile: fp32 global -> bf16 LDS, 16B chunks XOR-swizzled
    for (int c = tid; c < 4096; c += 768) {
      const int row = c >> 7, cid = c & 127;
      const float* sp = x + (size_t)(row0 + row) * C_ + cid * 8;
      float4 a = *(const float4*)(sp);
      float4 b = *(const float4*)(sp + 4);
      s16x8 pk = pack8(a, b);
      *(s16x8*)(tile + row * 1024 + ((cid ^ (row & 7)) * 8)) = pk;
    }
    __syncthreads();
    // ---- K-loop: B-frag from LDS (B[k][n=x-row]: n=l31, k=8*half+i)
    f32x16 acc = {};
#pragma unroll
    for (int ks = 0; ks < 32; ++ks) {
      const int chunk = 64 * kh + 2 * ks + half;
      s16x8 bf = *(const s16x8*)(tile + l31 * 1024 + ((chunk ^ (l31 & 7)) * 8));
      acc = __builtin_amdgcn_mfma_f32_32x32x16_bf16(wA[ks], bf, acc, 0, 0, 0);
    }
    __syncthreads();
    // ---- merge K-halves. C/D: col(lane&31)=x-row, row=(r&3)+8*(r>>2)+4*half
    if (kh == 1) {
      float* mp = mb + (ng * 32 + l31) * 33;
#pragma unroll
      for (int r = 0; r < 16; ++r)
        mp[(r & 3) + 8 * (r >> 2) + 4 * half] = acc[r];
    }
    __syncthreads();
    if (kh == 0) {
      const float* mp = mb + (ng * 32 + l31) * 33;
      const int rg = row0 + l31;  // global x row
#pragma unroll
      for (int g = 0; g < 4; ++g) {  // 4 groups of 4 consecutive W-rows
        const int rl0 = 8 * g + 4 * half;
        float s0 = acc[4 * g + 0] + mp[rl0 + 0];
        float s1 = acc[4 * g + 1] + mp[rl0 + 1];
        float s2 = acc[4 * g + 2] + mp[rl0 + 2];
        float s3 = acc[4 * g + 3] + mp[rl0 + 3];
        const int c = 32 * ng + rl0;  // output col in [0,192)
        if (ng < 2) {
          u16x4 pk = {f2b(s0), f2b(s1), f2b(s2), f2b(s3)};
          *(u16x4*)(qo + (size_t)rg * 64 + c) = pk;
        } else if (ng < 4) {
          u16x4 pk = {f2b(s0), f2b(s1), f2b(s2), f2b(s3)};
          *(u16x4*)(ko + (size_t)rg * 64 + (c - 64)) = pk;
        } else {
          const int d = c - 128;
          const int bb = rg >> 11, t0 = rg & 2047;
          u16* vp = vt + (size_t)bb * (64 * T_) + t0;
          vp[(size_t)(d + 0) * T_] = f2b(s0);
          vp[(size_t)(d + 1) * T_] = f2b(s1);
          vp[(size_t)(d + 2) * T_] = f2b(s2);
          vp[(size_t)(d + 3) * T_] = f2b(s3);
        }
      }
    }
    __syncthreads();
  }
}

// ---------------- kernel 2: causal flash attention, ping-pong K/V prefetch.
// q-tile = 32 rows; grid = 512 blocks, b = blk&7 (XCD-affine), qt = blk>>3.
// 4 waves split kv-tiles (j = w, w+4, ...) with private online-softmax state;
// tile j+4's K/V frags are issued before tile j's softmax/PV (two frag sets).
// S^T = K.Q^T (q in lane&15); PV as O^T = V^T.P^T; exp2 domain.
__global__ __launch_bounds__(256, 2) void attn(const u16* __restrict__ qw,
                                               const u16* __restrict__ kw,
                                               const u16* __restrict__ vt,
                                               float* __restrict__ out) {
  __shared__ __align__(16) u16 Pb[4 * 32 * 72];  // per-wave P; reused for O
  __shared__ float mbuf[4][32];
  __shared__ float lbuf[4][32];
  const int tid = threadIdx.x;
  const int wave = tid >> 6, lane = tid & 63;
  const int quad = lane >> 4, l15 = lane & 15;
  const int b = blockIdx.x & 7, qt = blockIdx.x >> 3;  // qt 0..63

  const u16* qp = qw + ((size_t)b * T_ + qt * 32) * 64;
  const u16* kb = kw + (size_t)b * T_ * 64;
  const u16* vb = vt + (size_t)b * 64 * T_;

  s16x8 qf[2][2];  // Q as B-operand: qf[nsub_q][kstep]
#pragma unroll
  for (int n = 0; n < 2; ++n)
#pragma unroll
    for (int ks = 0; ks < 2; ++ks)
      qf[n][ks] = *(const s16x8*)(qp + (16 * n + l15) * 64 + ks * 32 + quad * 8);

  f32x4 o[4][2];  // O^T accumulator: o[msub_d][nsub_q]
  float mr[2], lr[2];
#pragma unroll
  for (int m = 0; m < 4; ++m)
#pragma unroll
    for (int n = 0; n < 2; ++n) o[m][n] = {0.f, 0.f, 0.f, 0.f};
#pragma unroll
  for (int n = 0; n < 2; ++n) { mr[n] = -INFINITY; lr[n] = 0.0f; }

  u16* P = Pb + wave * (32 * 72);
  const int jd = qt >> 1;  // last (diagonal-overlapping) kv tile

  auto loadkv = [&](int j, s16x8 (&kf)[2][4], s16x8 (&vf)[2][4]) {
    const u16* kp = kb + (size_t)j * 64 * 64;
    const u16* vp = vb + j * 64;
#pragma unroll
    for (int ks = 0; ks < 2; ++ks)
#pragma unroll
      for (int m = 0; m < 4; ++m)
        kf[ks][m] = *(const s16x8*)(kp + (16 * m + l15) * 64 + ks * 32 + quad * 8);
#pragma unroll
    for (int ks = 0; ks < 2; ++ks)
#pragma unroll
      for (int m = 0; m < 4; ++m)
        vf[ks][m] = *(const s16x8*)(vp + (size_t)(16 * m + l15) * T_ + ks * 32 + quad * 8);
  };

  auto process = [&](int j, s16x8 (&kf)[2][4], s16x8 (&vf)[2][4]) {
    f32x4 s[4][2];  // S^T: s[msub_kv][nsub_q]
#pragma unroll
    for (int m = 0; m < 4; ++m)
#pragma unroll
      for (int n = 0; n < 2; ++n) s[m][n] = {0.f, 0.f, 0.f, 0.f};
#pragma unroll
    for (int ks = 0; ks < 2; ++ks)
#pragma unroll
      for (int m = 0; m < 4; ++m)
#pragma unroll
        for (int n = 0; n < 2; ++n)
          s[m][n] = __builtin_amdgcn_mfma_f32_16x16x32_bf16(kf[ks][m], qf[n][ks], s[m][n], 0, 0, 0);

    if (j == jd) {  // diagonal: kv_g = 64j+16m+quad*4+i, q_g = 32qt+16n+l15
#pragma unroll
      for (int m = 0; m < 4; ++m)
#pragma unroll
        for (int n = 0; n < 2; ++n)
#pragma unroll
          for (int i = 0; i < 4; ++i)
            if (64 * jd + 16 * m + quad * 4 + i > 32 * qt + 16 * n + l15)
              s[m][n][i] = -INFINITY;
    }
    float al[2];
#pragma unroll
    for (int n = 0; n < 2; ++n) {
      float mt = s[0][n][0];
#pragma unroll
      for (int m = 0; m < 4; ++m)
#pragma unroll
        for (int i = 0; i < 4; ++i) mt = fmaxf(mt, s[m][n][i]);
      mt = fmaxf(mt, __shfl_xor(mt, 16));
      mt = fmaxf(mt, __shfl_xor(mt, 32));
      float mn = fmaxf(mr[n], mt);
      al[n] = exp2f(mr[n] - mn);  // exp2(-inf)=0 on first tile
      mr[n] = mn;
      float rs = 0.0f;
#pragma unroll
      for (int m = 0; m < 4; ++m)
#pragma unroll
        for (int i = 0; i < 4; ++i) {
          float p = exp2f(s[m][n][i] - mn);
          s[m][n][i] = p;
          rs += p;
        }
      rs += __shfl_xor(rs, 16);
      rs += __shfl_xor(rs, 32);
      lr[n] = lr[n] * al[n] + rs;
    }
    // P -> LDS row-major [q][kv] (stride 72), packed 8B stores (wave-private)
#pragma unroll
    for (int n = 0; n < 2; ++n)
#pragma unroll
      for (int m = 0; m < 4; ++m) {
        u16x4 pk = {f2b(s[m][n][0]), f2b(s[m][n][1]), f2b(s[m][n][2]), f2b(s[m][n][3])};
        *(u16x4*)(&P[(16 * n + l15) * 72 + 16 * m + quad * 4]) = pk;
      }
#pragma unroll
    for (int m = 0; m < 4; ++m)
#pragma unroll
      for (int n = 0; n < 2; ++n) o[m][n] *= al[n];
    // O^T += V^T (A, regs) . P^T (B, LDS contiguous reads of P rows)
#pragma unroll
    for (int ks = 0; ks < 2; ++ks) {
      s16x8 pf[2];
#pragma unroll
      for (int n = 0; n < 2; ++n)
        pf[n] = *(const s16x8*)(&P[(16 * n + l15) * 72 + ks * 32 + quad * 8]);
#pragma unroll
      for (int m = 0; m < 4; ++m)
#pragma unroll
        for (int n = 0; n < 2; ++n)
          o[m][n] = __builtin_amdgcn_mfma_f32_16x16x32_bf16(vf[ks][m], pf[n], o[m][n], 0, 0, 0);
    }
  };

  s16x8 k0[2][4], v0[2][4], k1[2][4], v1[2][4];
  {
    int j = wave;
    if (j <= jd) loadkv(j, k0, v0);
    for (;;) {
      if (j > jd) break;
      if (j + 4 <= jd) loadkv(j + 4, k1, v1);  // prefetch before softmax/PV
      process(j, k0, v0);
      j += 4;
      if (j > jd) break;
      if (j + 4 <= jd) loadkv(j + 4, k0, v0);
      process(j, k1, v1);
      j += 4;
    }
  }
  // per-wave stats (value replicated across quads after xor16/32 reduce)
  if (quad == 0) {
#pragma unroll
    for (int n = 0; n < 2; ++n) {
      mbuf[wave][16 * n + l15] = mr[n];
      lbuf[wave][16 * n + l15] = lr[n];
    }
  }
  __syncthreads();  // all waves done with their P region before O reuse
  // O^T -> LDS as [q][d] bf16 over Pb, packed (i indexes consecutive d)
#pragma unroll
  for (int m = 0; m < 4; ++m)
#pragma unroll
    for (int n = 0; n < 2; ++n) {
      u16x4 pk = {f2b(o[m][n][0]), f2b(o[m][n][1]), f2b(o[m][n][2]), f2b(o[m][n][3])};
      *(u16x4*)(&Pb[wave * (32 * 72) + (16 * n + l15) * 72 + 16 * m + quad * 4]) = pk;
    }
  __syncthreads();
  // merge 4 wave-partials: thread handles q-row r, 8-wide d-chunk cg
  const int r = tid >> 3;          // 0..31
  const int cg = (tid & 7) * 8;    // 0..56
  float fw[4];
  float mstar = -INFINITY, lsum = 0.0f;
#pragma unroll
  for (int w = 0; w < 4; ++w) mstar = fmaxf(mstar, mbuf[w][r]);
#pragma unroll
  for (int w = 0; w < 4; ++w) {
    fw[w] = exp2f(mbuf[w][r] - mstar);
    lsum += fw[w] * lbuf[w][r];
  }
  const float inv = 1.0f / lsum;
  float accv[8];
#pragma unroll
  for (int e = 0; e < 8; ++e) accv[e] = 0.0f;
#pragma unroll
  for (int w = 0; w < 4; ++w) {
    s16x8 vv = *(const s16x8*)(&Pb[w * (32 * 72) + r * 72 + cg]);
#pragma unroll
    for (int e = 0; e < 8; ++e) {
      float f = __builtin_bit_cast(float, ((u32)(u16)vv[e]) << 16);
      accv[e] += fw[w] * f;
    }
  }
  float* op = out + ((size_t)b * T_ + qt * 32 + r) * 64 + cg;
  float4 st0 = {accv[0] * inv, accv[1] * inv, accv[2] * inv, accv[3] * inv};
  float4 st1 = {accv[4] * inv, accv[5] * inv, accv[6] * inv, accv[7] * inv};
  *(float4*)(op + 0) = st0;
  *(float4*)(op + 4) = st1;
}

extern "C" void kernel_launch(void* const* d_in, const int* in_sizes, int n_in,
                              void* d_out, int out_size, void* d_ws, size_t ws_size,
                              hipStream_t stream) {
  const float* x  = (const float*)d_in[0];
  const float* Wq = (const float*)d_in[1];
  const float* Wk = (const float*)d_in[2];
  const float* Wv = (const float*)d_in[3];
  float* out = (float*)d_out;
  char* ws = (char*)d_ws;
  u16* Wt = (u16*)ws;                                   // 192*1024*2 = 384 KB
  u16* q  = (u16*)(ws + 393216);                        // 2 MB
  u16* k  = (u16*)(ws + 393216 + 2097152);              // 2 MB
  u16* vT = (u16*)(ws + 393216 + 2 * 2097152);          // 2 MB
  hipLaunchKernelGGL(wconv, dim3(48), dim3(256), 0, stream, Wq, Wk, Wv, Wt);
  hipLaunchKernelGGL(proj, dim3(256), dim3(768), 0, stream, x, Wt, q, k, vT);
  hipLaunchKernelGGL(attn, dim3(512), dim3(256), 0, stream, q, k, vT, out);
}

// Round 5
// 173.320 us; speedup vs baseline: 1.0587x; 1.0587x over previous
//
#include <hip/hip_runtime.h>
#include <math.h>

typedef unsigned short u16;
typedef unsigned int u32;
typedef __attribute__((ext_vector_type(4))) float f32x4;
typedef __attribute__((ext_vector_type(8))) short s16x8;
typedef __attribute__((ext_vector_type(4))) unsigned short u16x4;

#define T_ 2048
#define C_ 1024

// fp32 -> bf16, round-half-up (max err 0.5 ulp, values always finite here)
__device__ __forceinline__ u16 f2b(float f) {
  u32 u = __builtin_bit_cast(u32, f);
  return (u16)((u + 0x8000u) >> 16);
}

// ---------------- kernel 0: weights fp32 [1024][64] x3 -> Wt bf16 [192][1024]
// transposed (k-contiguous), via LDS tile transpose (coalesced both sides).
// Softmax scale 1/8 AND log2(e) folded into W_q (softmax done in exp2 domain).
__global__ __launch_bounds__(256) void wconv(const float* __restrict__ Wq,
                                             const float* __restrict__ Wk,
                                             const float* __restrict__ Wv,
                                             u16* __restrict__ Wt) {
  __shared__ u16 t[64][68];
  const int bm = blockIdx.x >> 4;   // matrix 0..2
  const int kt = blockIdx.x & 15;   // k-tile of 64
  const float* src = (bm == 0) ? Wq : ((bm == 1) ? Wk : Wv);
  const float scale = (bm == 0) ? 0.18033688f : 1.0f;  // 0.125 * log2(e)
  const int krow = threadIdx.x >> 2;        // 0..63
  const int c0 = (threadIdx.x & 3) * 16;    // 0,16,32,48
  const float* sp = src + (size_t)(kt * 64 + krow) * 64 + c0;
#pragma unroll
  for (int i = 0; i < 4; ++i) {
    float4 v = *(const float4*)(sp + i * 4);
    t[c0 + i * 4 + 0][krow] = f2b(v.x * scale);
    t[c0 + i * 4 + 1][krow] = f2b(v.y * scale);
    t[c0 + i * 4 + 2][krow] = f2b(v.z * scale);
    t[c0 + i * 4 + 3][krow] = f2b(v.w * scale);
  }
  __syncthreads();
  const int n = threadIdx.x >> 2;
  const int koff = (threadIdx.x & 3) * 16;
  u16* dst = Wt + (size_t)(bm * 64 + n) * C_ + kt * 64 + koff;
#pragma unroll
  for (int i = 0; i < 4; ++i)
    *(u16x4*)(dst + i * 4) = *(const u16x4*)(&t[n][koff + i * 4]);
}

// ---------------- kernel 1: qkv projection — occupancy-first.
// 16 rows/block, grid 1024 (4 blocks/CU), 4 waves each owning 48 output cols.
// Per K-tile (64): stage x (fp32->bf16) into a tiny double-buffered LDS tile
// (ONE barrier/iter); W frags read directly from L2 (6 x 16B per wave); 6
// MFMAs. Low register count by design — TLP (16 waves/CU) hides latency, not
// register prefetch depth (R2-R4 showed the allocator vetoes that).
__global__ __launch_bounds__(256, 4) void proj(const float* __restrict__ x,
                                               const u16* __restrict__ Wt,
                                               u16* __restrict__ qo,
                                               u16* __restrict__ ko,
                                               u16* __restrict__ vt) {
  __shared__ __align__(16) u16 xs[2][16 * 72];  // x tile, stride 72
  const int tid = threadIdx.x;
  const int wave = tid >> 6, lane = tid & 63;
  const int quad = lane >> 4, l15 = lane & 15;
  const int m0 = blockIdx.x * 16;

  const int srow = tid >> 4;        // staging: row 0..15
  const int sc4 = (tid & 15) * 4;   // staging: 4-elem chunk
  const float* xp = x + (size_t)(m0 + srow) * C_ + sc4;
  const u16* wb = Wt + (size_t)(48 * wave + l15) * C_ + quad * 8;

  f32x4 acc[3];
  acc[0] = {0.f, 0.f, 0.f, 0.f};
  acc[1] = {0.f, 0.f, 0.f, 0.f};
  acc[2] = {0.f, 0.f, 0.f, 0.f};

  float4 xr = *(const float4*)(xp);

  for (int kt = 0; kt < 16; ++kt) {
    // stage current x chunk (reg -> bf16 -> LDS)
    u16x4 pk = {f2b(xr.x), f2b(xr.y), f2b(xr.z), f2b(xr.w)};
    *(u16x4*)(&xs[kt & 1][srow * 72 + sc4]) = pk;
    // W frags for this K-tile straight from L2 (n-rows 48w+16j+l15)
    const u16* wk = wb + kt * 64;
    s16x8 w0a = *(const s16x8*)(wk);
    s16x8 w1a = *(const s16x8*)(wk + 16 * C_);
    s16x8 w2a = *(const s16x8*)(wk + 32 * C_);
    s16x8 w0b = *(const s16x8*)(wk + 32);
    s16x8 w1b = *(const s16x8*)(wk + 16 * C_ + 32);
    s16x8 w2b = *(const s16x8*)(wk + 32 * C_ + 32);
    // prefetch next x chunk (HBM) — independent of this iter's compute
    if (kt < 15) xr = *(const float4*)(xp + (kt + 1) * 64);
    __syncthreads();  // staging of buf[kt&1] complete
    // A frags from LDS: A[m=l15][k=quad*8+i], ks in {0,1}
    s16x8 a0 = *(const s16x8*)(&xs[kt & 1][l15 * 72 + quad * 8]);
    s16x8 a1 = *(const s16x8*)(&xs[kt & 1][l15 * 72 + 32 + quad * 8]);
    acc[0] = __builtin_amdgcn_mfma_f32_16x16x32_bf16(a0, w0a, acc[0], 0, 0, 0);
    acc[1] = __builtin_amdgcn_mfma_f32_16x16x32_bf16(a0, w1a, acc[1], 0, 0, 0);
    acc[2] = __builtin_amdgcn_mfma_f32_16x16x32_bf16(a0, w2a, acc[2], 0, 0, 0);
    acc[0] = __builtin_amdgcn_mfma_f32_16x16x32_bf16(a1, w0b, acc[0], 0, 0, 0);
    acc[1] = __builtin_amdgcn_mfma_f32_16x16x32_bf16(a1, w1b, acc[1], 0, 0, 0);
    acc[2] = __builtin_amdgcn_mfma_f32_16x16x32_bf16(a1, w2b, acc[2], 0, 0, 0);
    // no second barrier: next iter stores to the other buffer, and any store
    // to THIS buffer is 2 iters away, past a barrier all waves' reads precede
  }

  // epilogue: C[m=x-row][n=w-col]; col=l15, row=quad*4+i per 16x16 subtile
  const int r0 = m0 + quad * 4;
#pragma unroll
  for (int j = 0; j < 3; ++j) {
    const int ns = wave * 3 + j;
    if (ns < 4) {
      const int col = ns * 16 + l15;
#pragma unroll
      for (int i = 0; i < 4; ++i)
        qo[(size_t)(r0 + i) * 64 + col] = f2b(acc[j][i]);
    } else if (ns < 8) {
      const int col = (ns - 4) * 16 + l15;
#pragma unroll
      for (int i = 0; i < 4; ++i)
        ko[(size_t)(r0 + i) * 64 + col] = f2b(acc[j][i]);
    } else {
      const int d = (ns - 8) * 16 + l15;
      const int bb = r0 >> 11, t0 = r0 & 2047;  // 4 consecutive t -> pack
      u16x4 pk = {f2b(acc[j][0]), f2b(acc[j][1]), f2b(acc[j][2]), f2b(acc[j][3])};
      *(u16x4*)(vt + (size_t)bb * (64 * T_) + (size_t)d * T_ + t0) = pk;
    }
  }
}

// ---------------- kernel 2: causal flash attention, ping-pong K/V prefetch.
// q-tile = 32 rows; grid = 512 blocks, b = blk&7 (XCD-affine), qt = blk>>3.
// 4 waves split kv-tiles (j = w, w+4, ...) with private online-softmax state;
// tile j+4's K/V frags are issued before tile j's softmax/PV (two frag sets).
// S^T = K.Q^T (q in lane&15); PV as O^T = V^T.P^T; exp2 domain.
__global__ __launch_bounds__(256, 2) void attn(const u16* __restrict__ qw,
                                               const u16* __restrict__ kw,
                                               const u16* __restrict__ vt,
                                               float* __restrict__ out) {
  __shared__ __align__(16) u16 Pb[4 * 32 * 72];  // per-wave P; reused for O
  __shared__ float mbuf[4][32];
  __shared__ float lbuf[4][32];
  const int tid = threadIdx.x;
  const int wave = tid >> 6, lane = tid & 63;
  const int quad = lane >> 4, l15 = lane & 15;
  const int b = blockIdx.x & 7, qt = blockIdx.x >> 3;  // qt 0..63

  const u16* qp = qw + ((size_t)b * T_ + qt * 32) * 64;
  const u16* kb = kw + (size_t)b * T_ * 64;
  const u16* vb = vt + (size_t)b * 64 * T_;

  s16x8 qf[2][2];  // Q as B-operand: qf[nsub_q][kstep]
#pragma unroll
  for (int n = 0; n < 2; ++n)
#pragma unroll
    for (int ks = 0; ks < 2; ++ks)
      qf[n][ks] = *(const s16x8*)(qp + (16 * n + l15) * 64 + ks * 32 + quad * 8);

  f32x4 o[4][2];  // O^T accumulator: o[msub_d][nsub_q]
  float mr[2], lr[2];
#pragma unroll
  for (int m = 0; m < 4; ++m)
#pragma unroll
    for (int n = 0; n < 2; ++n) o[m][n] = {0.f, 0.f, 0.f, 0.f};
#pragma unroll
  for (int n = 0; n < 2; ++n) { mr[n] = -INFINITY; lr[n] = 0.0f; }

  u16* P = Pb + wave * (32 * 72);
  const int jd = qt >> 1;  // last (diagonal-overlapping) kv tile

  auto loadkv = [&](int j, s16x8 (&kf)[2][4], s16x8 (&vf)[2][4]) {
    const u16* kp = kb + (size_t)j * 64 * 64;
    const u16* vp = vb + j * 64;
#pragma unroll
    for (int ks = 0; ks < 2; ++ks)
#pragma unroll
      for (int m = 0; m < 4; ++m)
        kf[ks][m] = *(const s16x8*)(kp + (16 * m + l15) * 64 + ks * 32 + quad * 8);
#pragma unroll
    for (int ks = 0; ks < 2; ++ks)
#pragma unroll
      for (int m = 0; m < 4; ++m)
        vf[ks][m] = *(const s16x8*)(vp + (size_t)(16 * m + l15) * T_ + ks * 32 + quad * 8);
  };

  auto process = [&](int j, s16x8 (&kf)[2][4], s16x8 (&vf)[2][4]) {
    f32x4 s[4][2];  // S^T: s[msub_kv][nsub_q]
#pragma unroll
    for (int m = 0; m < 4; ++m)
#pragma unroll
      for (int n = 0; n < 2; ++n) s[m][n] = {0.f, 0.f, 0.f, 0.f};
#pragma unroll
    for (int ks = 0; ks < 2; ++ks)
#pragma unroll
      for (int m = 0; m < 4; ++m)
#pragma unroll
        for (int n = 0; n < 2; ++n)
          s[m][n] = __builtin_amdgcn_mfma_f32_16x16x32_bf16(kf[ks][m], qf[n][ks], s[m][n], 0, 0, 0);

    if (j == jd) {  // diagonal: kv_g = 64j+16m+quad*4+i, q_g = 32qt+16n+l15
#pragma unroll
      for (int m = 0; m < 4; ++m)
#pragma unroll
        for (int n = 0; n < 2; ++n)
#pragma unroll
          for (int i = 0; i < 4; ++i)
            if (64 * jd + 16 * m + quad * 4 + i > 32 * qt + 16 * n + l15)
              s[m][n][i] = -INFINITY;
    }
    float al[2];
#pragma unroll
    for (int n = 0; n < 2; ++n) {
      float mt = s[0][n][0];
#pragma unroll
      for (int m = 0; m < 4; ++m)
#pragma unroll
        for (int i = 0; i < 4; ++i) mt = fmaxf(mt, s[m][n][i]);
      mt = fmaxf(mt, __shfl_xor(mt, 16));
      mt = fmaxf(mt, __shfl_xor(mt, 32));
      float mn = fmaxf(mr[n], mt);
      al[n] = exp2f(mr[n] - mn);  // exp2(-inf)=0 on first tile
      mr[n] = mn;
      float rs = 0.0f;
#pragma unroll
      for (int m = 0; m < 4; ++m)
#pragma unroll
        for (int i = 0; i < 4; ++i) {
          float p = exp2f(s[m][n][i] - mn);
          s[m][n][i] = p;
          rs += p;
        }
      rs += __shfl_xor(rs, 16);
      rs += __shfl_xor(rs, 32);
      lr[n] = lr[n] * al[n] + rs;
    }
    // P -> LDS row-major [q][kv] (stride 72), packed 8B stores (wave-private)
#pragma unroll
    for (int n = 0; n < 2; ++n)
#pragma unroll
      for (int m = 0; m < 4; ++m) {
        u16x4 pk = {f2b(s[m][n][0]), f2b(s[m][n][1]), f2b(s[m][n][2]), f2b(s[m][n][3])};
        *(u16x4*)(&P[(16 * n + l15) * 72 + 16 * m + quad * 4]) = pk;
      }
#pragma unroll
    for (int m = 0; m < 4; ++m)
#pragma unroll
      for (int n = 0; n < 2; ++n) o[m][n] *= al[n];
    // O^T += V^T (A, regs) . P^T (B, LDS contiguous reads of P rows)
#pragma unroll
    for (int ks = 0; ks < 2; ++ks) {
      s16x8 pf[2];
#pragma unroll
      for (int n = 0; n < 2; ++n)
        pf[n] = *(const s16x8*)(&P[(16 * n + l15) * 72 + ks * 32 + quad * 8]);
#pragma unroll
      for (int m = 0; m < 4; ++m)
#pragma unroll
        for (int n = 0; n < 2; ++n)
          o[m][n] = __builtin_amdgcn_mfma_f32_16x16x32_bf16(vf[ks][m], pf[n], o[m][n], 0, 0, 0);
    }
  };

  s16x8 k0[2][4], v0[2][4], k1[2][4], v1[2][4];
  {
    int j = wave;
    if (j <= jd) loadkv(j, k0, v0);
    for (;;) {
      if (j > jd) break;
      if (j + 4 <= jd) loadkv(j + 4, k1, v1);  // prefetch before softmax/PV
      process(j, k0, v0);
      j += 4;
      if (j > jd) break;
      if (j + 4 <= jd) loadkv(j + 4, k0, v0);
      process(j, k1, v1);
      j += 4;
    }
  }
  // per-wave stats (value replicated across quads after xor16/32 reduce)
  if (quad == 0) {
#pragma unroll
    for (int n = 0; n < 2; ++n) {
      mbuf[wave][16 * n + l15] = mr[n];
      lbuf[wave][16 * n + l15] = lr[n];
    }
  }
  __syncthreads();  // all waves done with their P region before O reuse
  // O^T -> LDS as [q][d] bf16 over Pb, packed (i indexes consecutive d)
#pragma unroll
  for (int m = 0; m < 4; ++m)
#pragma unroll
    for (int n = 0; n < 2; ++n) {
      u16x4 pk = {f2b(o[m][n][0]), f2b(o[m][n][1]), f2b(o[m][n][2]), f2b(o[m][n][3])};
      *(u16x4*)(&Pb[wave * (32 * 72) + (16 * n + l15) * 72 + 16 * m + quad * 4]) = pk;
    }
  __syncthreads();
  // merge 4 wave-partials: thread handles q-row r, 8-wide d-chunk cg
  const int r = tid >> 3;          // 0..31
  const int cg = (tid & 7) * 8;    // 0..56
  float fw[4];
  float mstar = -INFINITY, lsum = 0.0f;
#pragma unroll
  for (int w = 0; w < 4; ++w) mstar = fmaxf(mstar, mbuf[w][r]);
#pragma unroll
  for (int w = 0; w < 4; ++w) {
    fw[w] = exp2f(mbuf[w][r] - mstar);
    lsum += fw[w] * lbuf[w][r];
  }
  const float inv = 1.0f / lsum;
  float accv[8];
#pragma unroll
  for (int e = 0; e < 8; ++e) accv[e] = 0.0f;
#pragma unroll
  for (int w = 0; w < 4; ++w) {
    s16x8 vv = *(const s16x8*)(&Pb[w * (32 * 72) + r * 72 + cg]);
#pragma unroll
    for (int e = 0; e < 8; ++e) {
      float f = __builtin_bit_cast(float, ((u32)(u16)vv[e]) << 16);
      accv[e] += fw[w] * f;
    }
  }
  float* op = out + ((size_t)b * T_ + qt * 32 + r) * 64 + cg;
  float4 st0 = {accv[0] * inv, accv[1] * inv, accv[2] * inv, accv[3] * inv};
  float4 st1 = {accv[4] * inv, accv[5] * inv, accv[6] * inv, accv[7] * inv};
  *(float4*)(op + 0) = st0;
  *(float4*)(op + 4) = st1;
}

extern "C" void kernel_launch(void* const* d_in, const int* in_sizes, int n_in,
                              void* d_out, int out_size, void* d_ws, size_t ws_size,
                              hipStream_t stream) {
  const float* x  = (const float*)d_in[0];
  const float* Wq = (const float*)d_in[1];
  const float* Wk = (const float*)d_in[2];
  const float* Wv = (const float*)d_in[3];
  float* out = (float*)d_out;
  char* ws = (char*)d_ws;
  u16* Wt = (u16*)ws;                                   // 192*1024*2 = 384 KB
  u16* q  = (u16*)(ws + 393216);                        // 2 MB
  u16* k  = (u16*)(ws + 393216 + 2097152);              // 2 MB
  u16* vT = (u16*)(ws + 393216 + 2 * 2097152);          // 2 MB
  hipLaunchKernelGGL(wconv, dim3(48), dim3(256), 0, stream, Wq, Wk, Wv, Wt);
  hipLaunchKernelGGL(proj, dim3(1024), dim3(256), 0, stream, x, Wt, q, k, vT);
  hipLaunchKernelGGL(attn, dim3(512), dim3(256), 0, stream, q, k, vT, out);
}

// Round 6
// 151.837 us; speedup vs baseline: 1.2085x; 1.1415x over previous
//
#include <hip/hip_runtime.h>
#include <math.h>

typedef unsigned short u16;
typedef unsigned int u32;
typedef __attribute__((ext_vector_type(4))) float f32x4;
typedef __attribute__((ext_vector_type(8))) short s16x8;
typedef __attribute__((ext_vector_type(4))) unsigned short u16x4;

#define T_ 2048
#define C_ 1024

// fp32 -> bf16, round-half-up
__device__ __forceinline__ u16 f2b(float f) {
  u32 u = __builtin_bit_cast(u32, f);
  return (u16)((u + 0x8000u) >> 16);
}

__device__ __forceinline__ s16x8 pack8v(f32x4 a, f32x4 b) {
  s16x8 r;
  r[0] = (short)f2b(a[0]); r[1] = (short)f2b(a[1]);
  r[2] = (short)f2b(a[2]); r[3] = (short)f2b(a[3]);
  r[4] = (short)f2b(b[0]); r[5] = (short)f2b(b[1]);
  r[6] = (short)f2b(b[2]); r[7] = (short)f2b(b[3]);
  return r;
}

// async global->LDS, 16B per lane; LDS dest = wave-uniform base + lane*16
__device__ __forceinline__ void gld_lds16(const void* g, void* l) {
  __builtin_amdgcn_global_load_lds(
      (const __attribute__((address_space(1))) u32*)g,
      (__attribute__((address_space(3))) u32*)l, 16, 0, 0);
}

// ---------------- kernel 0: weights fp32 [1024][64] x3 -> Wt bf16 [192][1024]
// transposed (k-contiguous). Softmax scale 1/8 AND log2(e) folded into W_q.
__global__ __launch_bounds__(256) void wconv(const float* __restrict__ Wq,
                                             const float* __restrict__ Wk,
                                             const float* __restrict__ Wv,
                                             u16* __restrict__ Wt) {
  __shared__ u16 t[64][68];
  const int bm = blockIdx.x >> 4;   // matrix 0..2
  const int kt = blockIdx.x & 15;   // k-tile of 64
  const float* src = (bm == 0) ? Wq : ((bm == 1) ? Wk : Wv);
  const float scale = (bm == 0) ? 0.18033688f : 1.0f;  // 0.125 * log2(e)
  const int krow = threadIdx.x >> 2;
  const int c0 = (threadIdx.x & 3) * 16;
  const float* sp = src + (size_t)(kt * 64 + krow) * 64 + c0;
#pragma unroll
  for (int i = 0; i < 4; ++i) {
    float4 v = *(const float4*)(sp + i * 4);
    t[c0 + i * 4 + 0][krow] = f2b(v.x * scale);
    t[c0 + i * 4 + 1][krow] = f2b(v.y * scale);
    t[c0 + i * 4 + 2][krow] = f2b(v.z * scale);
    t[c0 + i * 4 + 3][krow] = f2b(v.w * scale);
  }
  __syncthreads();
  const int n = threadIdx.x >> 2;
  const int koff = (threadIdx.x & 3) * 16;
  u16* dst = Wt + (size_t)(bm * 64 + n) * C_ + kt * 64 + koff;
#pragma unroll
  for (int i = 0; i < 4; ++i)
    *(u16x4*)(dst + i * 4) = *(const u16x4*)(&t[n][koff + i * 4]);
}

// ---------------- kernel 1: qkv projection — m97-clone (2-barrier K-loop,
// global_load_lds width=16 for BOTH x and W; all MFMA frags from LDS).
// M-tile 32, grid 512 (2 blocks/CU), 4 waves = 2 m-subtiles x 2 n-halves.
// 16B chunks XOR-swizzled on the GLOBAL side (LDS side of global_load_lds is
// lane-major fixed) so ds_read_b128 frag reads are 2-way (= free) banked.
__global__ __launch_bounds__(256, 2) void proj(const float* __restrict__ x,
                                               const u16* __restrict__ Wt,
                                               u16* __restrict__ qo,
                                               u16* __restrict__ ko,
                                               u16* __restrict__ vt) {
  __shared__ __align__(16) float xs[32 * 64];   // 8 KB fp32 x-tile
  __shared__ __align__(16) u16 wsh[192 * 64];   // 24 KB bf16 W-slice
  const int tid = threadIdx.x;
  const int wave = tid >> 6, lane = tid & 63;
  const int quad = lane >> 4, l15 = lane & 15;
  const int mg = wave >> 1, nh = wave & 1;
  const int m0 = blockIdx.x * 32;

  // x staging: wave w stages rows 8w..8w+7 in 2 calls of 4 rows (1 KB each).
  // slot s=(lane&15) of row r holds global 16B-chunk g = s ^ (r&15).
  const int xrow_in = lane >> 4;     // 0..3 within call
  const int xslot = lane & 15;
  // W staging: wave w stages rows 48w..48w+47 in 6 calls of 8 rows (1 KB).
  // slot s=(lane&7) of row r holds global chunk g = s ^ (r&7).
  const int wrow_in = lane >> 3;     // 0..7 within call
  const int wg = (lane & 7) ^ wrow_in;

  f32x4 acc[6];
#pragma unroll
  for (int j = 0; j < 6; ++j) acc[j] = {0.f, 0.f, 0.f, 0.f};

  for (int kt = 0; kt < 16; ++kt) {
    // ---- stage x (2 calls/wave)
#pragma unroll
    for (int c = 0; c < 2; ++c) {
      const int row = 8 * wave + 4 * c + xrow_in;
      const int g = xslot ^ (row & 15);
      gld_lds16(x + (size_t)(m0 + row) * C_ + kt * 64 + g * 4,
                &xs[(8 * wave + 4 * c) * 64]);
    }
    // ---- stage W (6 calls/wave)
#pragma unroll
    for (int c = 0; c < 6; ++c) {
      const int row = (6 * wave + c) * 8 + wrow_in;
      gld_lds16(Wt + (size_t)row * C_ + kt * 64 + wg * 8,
                &wsh[(6 * wave + c) * 8 * 64]);
    }
    __syncthreads();  // compiler drains vmcnt here (m97 tax)
    // ---- A frags: x rows 16*mg+l15, k = ks*32+quad*8+i (fp32 -> bf16 pack)
    s16x8 af[2];
#pragma unroll
    for (int ks = 0; ks < 2; ++ks) {
      const int row = 16 * mg + l15;
      const int cc = ks * 8 + quad * 2;
      f32x4 p0 = *(const f32x4*)&xs[row * 64 + ((cc ^ (row & 15)) * 4)];
      f32x4 p1 = *(const f32x4*)&xs[row * 64 + (((cc + 1) ^ (row & 15)) * 4)];
      af[ks] = pack8v(p0, p1);
    }
    // ---- B frags + MFMA: W rows (nh*6+jj)*16 + l15, chunk ks*4+quad
#pragma unroll
    for (int jj = 0; jj < 6; ++jj) {
      const int row = (nh * 6 + jj) * 16 + l15;
#pragma unroll
      for (int ks = 0; ks < 2; ++ks) {
        const int cc = ks * 4 + quad;
        s16x8 bf = *(const s16x8*)&wsh[row * 64 + ((cc ^ (row & 7)) * 8)];
        acc[jj] = __builtin_amdgcn_mfma_f32_16x16x32_bf16(af[ks], bf, acc[jj], 0, 0, 0);
      }
    }
    __syncthreads();  // tile fully consumed before next stage overwrites
  }

  // epilogue: C[m=x-row][n=W-row]; col=l15 (n), row=quad*4+i (m)
  const int r0 = m0 + 16 * mg + quad * 4;
#pragma unroll
  for (int jj = 0; jj < 6; ++jj) {
    const int ns = nh * 6 + jj;
    if (ns < 4) {
      const int col = ns * 16 + l15;
#pragma unroll
      for (int i = 0; i < 4; ++i)
        qo[(size_t)(r0 + i) * 64 + col] = f2b(acc[jj][i]);
    } else if (ns < 8) {
      const int col = (ns - 4) * 16 + l15;
#pragma unroll
      for (int i = 0; i < 4; ++i)
        ko[(size_t)(r0 + i) * 64 + col] = f2b(acc[jj][i]);
    } else {
      const int d = (ns - 8) * 16 + l15;
      const int bb = r0 >> 11, t0 = r0 & 2047;
      u16x4 pk = {f2b(acc[jj][0]), f2b(acc[jj][1]), f2b(acc[jj][2]), f2b(acc[jj][3])};
      *(u16x4*)(vt + (size_t)bb * (64 * T_) + (size_t)d * T_ + t0) = pk;
    }
  }
}

// ---------------- kernel 2: causal flash attention — TLP-first.
// q-tile 16 rows; grid 1024 = 4 blocks/CU = 16 waves/CU; b = blk&7
// (XCD-affine), qt heavy-first. 4 waves split kv-tiles (j = w, w+4, ...),
// private online-softmax state, NO in-loop barriers, no register prefetch
// (compiler sinks it — R2/R4). S^T = K.Q^T; PV as O^T = V^T.P^T; exp2 domain.
__global__ __launch_bounds__(256, 4) void attn(const u16* __restrict__ qw,
                                               const u16* __restrict__ kw,
                                               const u16* __restrict__ vt,
                                               float* __restrict__ out) {
  __shared__ __align__(16) u16 Pb[4][16 * 72];  // per-wave P; reused for O
  __shared__ float mbuf[4][16];
  __shared__ float lbuf[4][16];
  const int tid = threadIdx.x;
  const int wave = tid >> 6, lane = tid & 63;
  const int quad = lane >> 4, l15 = lane & 15;
  const int b = blockIdx.x & 7;
  const int qt = 127 - (blockIdx.x >> 3);  // heavy q-tiles first

  const u16* qp = qw + ((size_t)b * T_ + qt * 16) * 64;
  const u16* kb = kw + (size_t)b * T_ * 64;
  const u16* vb = vt + (size_t)b * 64 * T_;

  s16x8 qf[2];  // Q as B-operand: q-row n = l15, k = ks*32+quad*8+i
#pragma unroll
  for (int ks = 0; ks < 2; ++ks)
    qf[ks] = *(const s16x8*)(qp + l15 * 64 + ks * 32 + quad * 8);

  f32x4 o[4];  // O^T acc: subtile m over d, col = q = l15
#pragma unroll
  for (int m = 0; m < 4; ++m) o[m] = {0.f, 0.f, 0.f, 0.f};
  float mr = -INFINITY, lr = 0.0f;

  u16* P = Pb[wave];
  const int jd = qt >> 2;  // last (diagonal-overlapping) 64-wide kv tile

  for (int j = wave; j <= jd; j += 4) {
    const u16* kp = kb + (size_t)j * 64 * 64;
    const u16* vp = vb + j * 64;
    s16x8 kf[2][4], vf[2][4];
#pragma unroll
    for (int ks = 0; ks < 2; ++ks)
#pragma unroll
      for (int m = 0; m < 4; ++m)
        kf[ks][m] = *(const s16x8*)(kp + (16 * m + l15) * 64 + ks * 32 + quad * 8);
#pragma unroll
    for (int ks = 0; ks < 2; ++ks)
#pragma unroll
      for (int m = 0; m < 4; ++m)
        vf[ks][m] = *(const s16x8*)(vp + (size_t)(16 * m + l15) * T_ + ks * 32 + quad * 8);

    f32x4 s[4];  // S^T: kv subtile m, q col = l15
#pragma unroll
    for (int m = 0; m < 4; ++m) s[m] = {0.f, 0.f, 0.f, 0.f};
#pragma unroll
    for (int ks = 0; ks < 2; ++ks)
#pragma unroll
      for (int m = 0; m < 4; ++m)
        s[m] = __builtin_amdgcn_mfma_f32_16x16x32_bf16(kf[ks][m], qf[ks], s[m], 0, 0, 0);

    if (j == jd) {  // diagonal: kv_g = 64j+16m+quad*4+i vs q_g = 16qt+l15
#pragma unroll
      for (int m = 0; m < 4; ++m)
#pragma unroll
        for (int i = 0; i < 4; ++i)
          if (64 * jd + 16 * m + quad * 4 + i > 16 * qt + l15) s[m][i] = -INFINITY;
    }
    // online softmax over 16 in-lane values + cross-quad (xor16, xor32)
    float mt = s[0][0];
#pragma unroll
    for (int m = 0; m < 4; ++m)
#pragma unroll
      for (int i = 0; i < 4; ++i) mt = fmaxf(mt, s[m][i]);
    mt = fmaxf(mt, __shfl_xor(mt, 16));
    mt = fmaxf(mt, __shfl_xor(mt, 32));
    const float mn = fmaxf(mr, mt);
    const float al = exp2f(mr - mn);
    mr = mn;
    float rs = 0.0f;
#pragma unroll
    for (int m = 0; m < 4; ++m)
#pragma unroll
      for (int i = 0; i < 4; ++i) {
        float p = exp2f(s[m][i] - mn);
        s[m][i] = p;
        rs += p;
      }
    rs += __shfl_xor(rs, 16);
    rs += __shfl_xor(rs, 32);
    lr = lr * al + rs;
    // P -> LDS row-major [q=l15][kv] (stride 72), packed 8B (wave-private)
#pragma unroll
    for (int m = 0; m < 4; ++m) {
      u16x4 pk = {f2b(s[m][0]), f2b(s[m][1]), f2b(s[m][2]), f2b(s[m][3])};
      *(u16x4*)(&P[l15 * 72 + 16 * m + quad * 4]) = pk;
    }
#pragma unroll
    for (int m = 0; m < 4; ++m) o[m] *= al;
    // O^T += V^T (A, regs) . P^T (B: n=q=l15, k from P row)
#pragma unroll
    for (int ks = 0; ks < 2; ++ks) {
      s16x8 pf = *(const s16x8*)(&P[l15 * 72 + ks * 32 + quad * 8]);
#pragma unroll
      for (int m = 0; m < 4; ++m)
        o[m] = __builtin_amdgcn_mfma_f32_16x16x32_bf16(vf[ks][m], pf, o[m], 0, 0, 0);
    }
  }
  // stats (replicated across quads post-reduce) + O^T -> LDS [q=l15][d] bf16
  if (quad == 0) {
    mbuf[wave][l15] = mr;
    lbuf[wave][l15] = lr;
  }
#pragma unroll
  for (int m = 0; m < 4; ++m) {
    u16x4 pk = {f2b(o[m][0]), f2b(o[m][1]), f2b(o[m][2]), f2b(o[m][3])};
    *(u16x4*)(&Pb[wave][l15 * 72 + 16 * m + quad * 4]) = pk;
  }
  __syncthreads();
  // merge 4 wave-partials: thread -> q-row r (16), d-chunk cg (4 wide)
  const int r = tid >> 4;
  const int cg = (tid & 15) * 4;
  float fw[4];
  float mstar = -INFINITY, lsum = 0.0f;
#pragma unroll
  for (int w = 0; w < 4; ++w) mstar = fmaxf(mstar, mbuf[w][r]);
#pragma unroll
  for (int w = 0; w < 4; ++w) {
    fw[w] = exp2f(mbuf[w][r] - mstar);
    lsum += fw[w] * lbuf[w][r];
  }
  const float inv = 1.0f / lsum;
  float a0 = 0.f, a1 = 0.f, a2 = 0.f, a3 = 0.f;
#pragma unroll
  for (int w = 0; w < 4; ++w) {
    u16x4 vv = *(const u16x4*)(&Pb[w][r * 72 + cg]);
    a0 += fw[w] * __builtin_bit_cast(float, ((u32)vv[0]) << 16);
    a1 += fw[w] * __builtin_bit_cast(float, ((u32)vv[1]) << 16);
    a2 += fw[w] * __builtin_bit_cast(float, ((u32)vv[2]) << 16);
    a3 += fw[w] * __builtin_bit_cast(float, ((u32)vv[3]) << 16);
  }
  float4 st = {a0 * inv, a1 * inv, a2 * inv, a3 * inv};
  *(float4*)(out + ((size_t)b * T_ + qt * 16 + r) * 64 + cg) = st;
}

extern "C" void kernel_launch(void* const* d_in, const int* in_sizes, int n_in,
                              void* d_out, int out_size, void* d_ws, size_t ws_size,
                              hipStream_t stream) {
  const float* x  = (const float*)d_in[0];
  const float* Wq = (const float*)d_in[1];
  const float* Wk = (const float*)d_in[2];
  const float* Wv = (const float*)d_in[3];
  float* out = (float*)d_out;
  char* ws = (char*)d_ws;
  u16* Wt = (u16*)ws;                                   // 384 KB
  u16* q  = (u16*)(ws + 393216);                        // 2 MB
  u16* k  = (u16*)(ws + 393216 + 2097152);              // 2 MB
  u16* vT = (u16*)(ws + 393216 + 2 * 2097152);          // 2 MB
  hipLaunchKernelGGL(wconv, dim3(48), dim3(256), 0, stream, Wq, Wk, Wv, Wt);
  hipLaunchKernelGGL(proj, dim3(512), dim3(256), 0, stream, x, Wt, q, k, vT);
  hipLaunchKernelGGL(attn, dim3(1024), dim3(256), 0, stream, q, k, vT, out);
}